// Round 12
// baseline (234.508 us; speedup 1.0000x reference)
//
#include <hip/hip_runtime.h>

typedef _Float16 half8  __attribute__((ext_vector_type(8)));
typedef _Float16 half4v __attribute__((ext_vector_type(4)));
typedef _Float16 half2v __attribute__((ext_vector_type(2)));
typedef float    floatx4 __attribute__((ext_vector_type(4)));
typedef float    float2v __attribute__((ext_vector_type(2)));

static constexpr float INV2PI = 0.15915494309189535f;  // fold rad->rev into weights
static constexpr float RLOG   = 3.82843f;

// Fused activation: x0 = 0.5+0.5cos(2*pi*a); two logistic iters.
// With u = cos^2:  p = (1-u)/4,  h = R^2 p (1 - R p) = A + u*(B + D*u).
static constexpr double RD = (double)RLOG;
static constexpr float ACT_A = (float)(RD*RD/4.0 - RD*RD*RD/16.0);
static constexpr float ACT_B = (float)(-RD*RD/4.0 + RD*RD*RD/8.0);
static constexpr float ACT_D = (float)(-RD*RD*RD/16.0);

__device__ __forceinline__ float act_rev(float a) {
    float c = __builtin_amdgcn_cosf(a);
    float u = c * c;
    float t = __builtin_fmaf(ACT_D, u, ACT_B);
    return __builtin_fmaf(u, t, ACT_A);
}

// Two C-frags (tiles t, t+2) -> next-layer B-frag directly (no cat shuffles).
// Per 2 activations: 2x v_cos + 3 packed-f32 ops.
__device__ __forceinline__ half8 act8(floatx4 a, floatx4 b) {
    float2v c0 = { __builtin_amdgcn_cosf(a[0]), __builtin_amdgcn_cosf(a[1]) };
    float2v c1 = { __builtin_amdgcn_cosf(a[2]), __builtin_amdgcn_cosf(a[3]) };
    float2v c2 = { __builtin_amdgcn_cosf(b[0]), __builtin_amdgcn_cosf(b[1]) };
    float2v c3 = { __builtin_amdgcn_cosf(b[2]), __builtin_amdgcn_cosf(b[3]) };
    float2v u0 = c0*c0, u1 = c1*c1, u2 = c2*c2, u3 = c3*c3;
    float2v t0 = __builtin_elementwise_fma(u0, (float2v)(ACT_D), (float2v)(ACT_B));
    float2v t1 = __builtin_elementwise_fma(u1, (float2v)(ACT_D), (float2v)(ACT_B));
    float2v t2 = __builtin_elementwise_fma(u2, (float2v)(ACT_D), (float2v)(ACT_B));
    float2v t3 = __builtin_elementwise_fma(u3, (float2v)(ACT_D), (float2v)(ACT_B));
    float2v h0 = __builtin_elementwise_fma(u0, t0, (float2v)(ACT_A));
    float2v h1 = __builtin_elementwise_fma(u1, t1, (float2v)(ACT_A));
    float2v h2 = __builtin_elementwise_fma(u2, t2, (float2v)(ACT_A));
    float2v h3 = __builtin_elementwise_fma(u3, t3, (float2v)(ACT_A));
    half2v e0 = __builtin_bit_cast(half2v, __builtin_amdgcn_cvt_pkrtz(h0.x, h0.y));
    half2v e1 = __builtin_bit_cast(half2v, __builtin_amdgcn_cvt_pkrtz(h1.x, h1.y));
    half2v e2 = __builtin_bit_cast(half2v, __builtin_amdgcn_cvt_pkrtz(h2.x, h2.y));
    half2v e3 = __builtin_bit_cast(half2v, __builtin_amdgcn_cvt_pkrtz(h3.x, h3.y));
    half4v lo = __builtin_shufflevector(e0, e1, 0, 1, 2, 3);
    half4v hi = __builtin_shufflevector(e2, e3, 0, 1, 2, 3);
    return __builtin_shufflevector(lo, hi, 0, 1, 2, 3, 4, 5, 6, 7);
}

// Per-block LDS cache: w2/w3 A-frags ONLY (R11 showed the LDS pipe at ~62%
// busy, co-dominant with VALU; biases move back to registers -- 16 regs fit
// easily now that VGPR=32 vs cap 64 -- cutting LDS reads/tile 24 -> 16).
// 512-thread block, 4 resident blocks/CU = 32 waves/CU ceiling at 86KB LDS.
struct SMem {
    half8 w2[8][64];   // [(t*2+c)][lane]
    half8 w3[8][64];
};

__global__ __launch_bounds__(512, 8) void mlp_fused(
    const float* __restrict__ x,
    const float* __restrict__ W1, const float* __restrict__ b1,
    const float* __restrict__ W2, const float* __restrict__ b2,
    const float* __restrict__ W3, const float* __restrict__ b3,
    const float* __restrict__ W4, const float* __restrict__ b4,
    float* __restrict__ out, int N)
{
    __shared__ SMem sm;
    const int lane = threadIdx.x & 63;
    const int wib  = threadIdx.x >> 6;   // 0..7
    const int m    = lane & 15;   // sample / C col / A row
    const int q    = lane >> 4;   // quad
    const float s  = INV2PI;
    const floatx4 zero4 = {0.0f, 0.0f, 0.0f, 0.0f};

    // ---- in-register persistent frags: L1, L4, and (back again) biases ----
    // L1 A-frag (tile t), lanes q==0: [w0h, w0h, w0l, w1h, w1h, w1l, b1h, b1l]
    half8 w1f[4];
    #pragma unroll
    for (int t = 0; t < 4; ++t) {
        half8 v = {};
        if (q == 0) {
            const int n = 16 * t + m;
            float w0 = W1[2*n] * s, w1 = W1[2*n+1] * s, bb = b1[n] * s;
            _Float16 w0h = (_Float16)w0; float w0l = w0 - (float)w0h;
            _Float16 w1h = (_Float16)w1; float w1l = w1 - (float)w1h;
            _Float16 bh  = (_Float16)bb; float bl  = bb - (float)bh;
            v[0] = w0h; v[1] = w0h; v[2] = (_Float16)w0l;
            v[3] = w1h; v[4] = w1h; v[5] = (_Float16)w1l;
            v[6] = bh;  v[7] = (_Float16)bl;
        }
        w1f[t] = v;
    }
    // L4 A-frag: only out-row m==0 real; sigma column permutation
    //   sigma: k-slot (c,q,j) -> neuron (j<4 ? 16c+4q+j : 16(c+2)+4q+j-4)
    half8 w4f[2] = {half8{}, half8{}};
    if (m == 0) {
        #pragma unroll
        for (int c = 0; c < 2; ++c)
            #pragma unroll
            for (int j = 0; j < 8; ++j) {
                int nu = (j < 4) ? (16 * c + 4 * q + j) : (16 * (c + 2) + 4 * q + j - 4);
                w4f[c][j] = (_Float16)(W4[nu] * s);
            }
    }
    floatx4 a4init = zero4;
    if (q == 0) a4init[0] = b4[0] * s;       // C row 0 = (q=0, r=0)

    // Bias C-frags in registers (loop-invariant, 16 VGPRs total).
    floatx4 bb2[4], bb3[4];
    #pragma unroll
    for (int t = 0; t < 4; ++t) {
        bb2[t] = *(const floatx4*)(b2 + 16 * t + 4 * q) * s;
        bb3[t] = *(const floatx4*)(b3 + 16 * t + 4 * q) * s;
    }

    // ---- wave-split LDS prep (sigma-permuted columns), one barrier ----
    if (wib == 0) {
        #pragma unroll
        for (int t = 0; t < 4; ++t) {
            const float* r2 = W2 + (16 * t + m) * 64;
            #pragma unroll
            for (int c = 0; c < 2; ++c) {
                floatx4 lo2 = *(const floatx4*)(r2 + 16 * c + 4 * q);
                floatx4 hi2 = *(const floatx4*)(r2 + 16 * (c + 2) + 4 * q);
                half8 v2;
                #pragma unroll
                for (int j = 0; j < 4; ++j) {
                    v2[j]     = (_Float16)(lo2[j] * s);
                    v2[4 + j] = (_Float16)(hi2[j] * s);
                }
                sm.w2[t * 2 + c][lane] = v2;
            }
        }
    } else if (wib == 1) {
        #pragma unroll
        for (int t = 0; t < 4; ++t) {
            const float* r3 = W3 + (16 * t + m) * 64;
            #pragma unroll
            for (int c = 0; c < 2; ++c) {
                floatx4 lo3 = *(const floatx4*)(r3 + 16 * c + 4 * q);
                floatx4 hi3 = *(const floatx4*)(r3 + 16 * (c + 2) + 4 * q);
                half8 v3;
                #pragma unroll
                for (int j = 0; j < 4; ++j) {
                    v3[j]     = (_Float16)(lo3[j] * s);
                    v3[4 + j] = (_Float16)(hi3[j] * s);
                }
                sm.w3[t * 2 + c][lane] = v3;
            }
        }
    }
    __syncthreads();

    const int ntiles = N >> 4;
    const int nwaves = (gridDim.x * blockDim.x) >> 6;
    const int gwave  = (int)(blockIdx.x * blockDim.x + threadIdx.x) >> 6;
    const float2* __restrict__ x2 = (const float2*)x;

    int tile = gwave;
    float2 xv = x2[(tile << 4) + m];          // 1-ahead x prefetch
    while (tile < ntiles) {
        const int nt = tile + nwaves;
        float2 xnext;
        if (nt < ntiles) xnext = x2[(nt << 4) + m];

        // L1 B-frag (lanes q==0): [xh, xl, xh, yh, yl, yh, 1, 1]
        half8 xa = {};
        if (q == 0) {
            _Float16 xh = (_Float16)xv.x; float xl = xv.x - (float)xh;
            _Float16 yh = (_Float16)xv.y; float yl = xv.y - (float)yh;
            xa[0] = xh; xa[1] = (_Float16)xl; xa[2] = xh;
            xa[3] = yh; xa[4] = (_Float16)yl; xa[5] = yh;
            xa[6] = (_Float16)1.0f; xa[7] = (_Float16)1.0f;
        }

        // ---- layer 1 (in-register frags) ----
        floatx4 a0 = __builtin_amdgcn_mfma_f32_16x16x32_f16(w1f[0], xa, zero4, 0, 0, 0);
        floatx4 a1 = __builtin_amdgcn_mfma_f32_16x16x32_f16(w1f[1], xa, zero4, 0, 0, 0);
        floatx4 a2 = __builtin_amdgcn_mfma_f32_16x16x32_f16(w1f[2], xa, zero4, 0, 0, 0);
        floatx4 a3 = __builtin_amdgcn_mfma_f32_16x16x32_f16(w1f[3], xa, zero4, 0, 0, 0);
        half8 B0 = act8(a0, a2);
        half8 B1 = act8(a1, a3);

        // Opaque zero per layer: defeats LICM on the weight reads (else they
        // hoist back into ~96 live regs and spill) AND staggers the reads so
        // peak staging is one layer's worth.
        int z2 = 0; asm volatile("" : "+v"(z2));
        const int l2i = lane + z2;
        a0 = __builtin_amdgcn_mfma_f32_16x16x32_f16(sm.w2[0][l2i], B0, bb2[0], 0, 0, 0);
        a1 = __builtin_amdgcn_mfma_f32_16x16x32_f16(sm.w2[2][l2i], B0, bb2[1], 0, 0, 0);
        a2 = __builtin_amdgcn_mfma_f32_16x16x32_f16(sm.w2[4][l2i], B0, bb2[2], 0, 0, 0);
        a3 = __builtin_amdgcn_mfma_f32_16x16x32_f16(sm.w2[6][l2i], B0, bb2[3], 0, 0, 0);
        a0 = __builtin_amdgcn_mfma_f32_16x16x32_f16(sm.w2[1][l2i], B1, a0, 0, 0, 0);
        a1 = __builtin_amdgcn_mfma_f32_16x16x32_f16(sm.w2[3][l2i], B1, a1, 0, 0, 0);
        a2 = __builtin_amdgcn_mfma_f32_16x16x32_f16(sm.w2[5][l2i], B1, a2, 0, 0, 0);
        a3 = __builtin_amdgcn_mfma_f32_16x16x32_f16(sm.w2[7][l2i], B1, a3, 0, 0, 0);
        half8 C0 = act8(a0, a2);
        half8 C1 = act8(a1, a3);

        int z3 = 0; asm volatile("" : "+v"(z3));
        const int l3i = lane + z3;
        a0 = __builtin_amdgcn_mfma_f32_16x16x32_f16(sm.w3[0][l3i], C0, bb3[0], 0, 0, 0);
        a1 = __builtin_amdgcn_mfma_f32_16x16x32_f16(sm.w3[2][l3i], C0, bb3[1], 0, 0, 0);
        a2 = __builtin_amdgcn_mfma_f32_16x16x32_f16(sm.w3[4][l3i], C0, bb3[2], 0, 0, 0);
        a3 = __builtin_amdgcn_mfma_f32_16x16x32_f16(sm.w3[6][l3i], C0, bb3[3], 0, 0, 0);
        a0 = __builtin_amdgcn_mfma_f32_16x16x32_f16(sm.w3[1][l3i], C1, a0, 0, 0, 0);
        a1 = __builtin_amdgcn_mfma_f32_16x16x32_f16(sm.w3[3][l3i], C1, a1, 0, 0, 0);
        a2 = __builtin_amdgcn_mfma_f32_16x16x32_f16(sm.w3[5][l3i], C1, a2, 0, 0, 0);
        a3 = __builtin_amdgcn_mfma_f32_16x16x32_f16(sm.w3[7][l3i], C1, a3, 0, 0, 0);
        half8 D0 = act8(a0, a2);
        half8 D1 = act8(a1, a3);

        // ---- layer 4 + store ----
        floatx4 a4 = __builtin_amdgcn_mfma_f32_16x16x32_f16(w4f[0], D0, a4init, 0, 0, 0);
        a4 = __builtin_amdgcn_mfma_f32_16x16x32_f16(w4f[1], D1, a4, 0, 0, 0);
        if (q == 0)
            out[(tile << 4) + m] = act_rev(a4[0]);

        xv = xnext;
        tile = nt;
    }
}

extern "C" void kernel_launch(void* const* d_in, const int* in_sizes, int n_in,
                              void* d_out, int out_size, void* d_ws, size_t ws_size,
                              hipStream_t stream) {
    const float* x  = (const float*)d_in[0];
    const float* W1 = (const float*)d_in[1];
    const float* b1 = (const float*)d_in[2];
    const float* W2 = (const float*)d_in[3];
    const float* b2 = (const float*)d_in[4];
    const float* W3 = (const float*)d_in[5];
    const float* b3 = (const float*)d_in[6];
    const float* W4 = (const float*)d_in[7];
    const float* b4 = (const float*)d_in[8];
    float* out = (float*)d_out;
    const int N = out_size;          // 2097152, divisible by 16

    // 1024 blocks x 8 waves = 8192 waves, ALL resident at once (4 blocks/CU);
    // 131072 tiles -> exactly 16 tiles/wave. Single dispatch round.
    mlp_fused<<<dim3(1024), dim3(512), 0, stream>>>(x, W1, b1, W2, b2, W3, b3, W4, b4, out, N);
}

// Round 13
// 160.559 us; speedup vs baseline: 1.4606x; 1.4606x over previous
//
#include <hip/hip_runtime.h>

typedef _Float16 half8  __attribute__((ext_vector_type(8)));
typedef _Float16 half4v __attribute__((ext_vector_type(4)));
typedef _Float16 half2v __attribute__((ext_vector_type(2)));
typedef float    floatx4 __attribute__((ext_vector_type(4)));
typedef float    float2v __attribute__((ext_vector_type(2)));

static constexpr float INV2PI = 0.15915494309189535f;  // fold rad->rev into weights
static constexpr float RLOG   = 3.82843f;

// Fused activation: x0 = 0.5+0.5cos(2*pi*a); two logistic iters.
// With u = cos^2:  p = (1-u)/4,  h = R^2 p (1 - R p) = A + u*(B + D*u).
static constexpr double RD = (double)RLOG;
static constexpr float ACT_A = (float)(RD*RD/4.0 - RD*RD*RD/16.0);
static constexpr float ACT_B = (float)(-RD*RD/4.0 + RD*RD*RD/8.0);
static constexpr float ACT_D = (float)(-RD*RD*RD/16.0);

__device__ __forceinline__ float act_rev(float a) {
    float c = __builtin_amdgcn_cosf(a);
    float u = c * c;
    float t = __builtin_fmaf(ACT_D, u, ACT_B);
    return __builtin_fmaf(u, t, ACT_A);
}

// Two C-frags (tiles t, t+2) -> next-layer B-frag directly (no cat shuffles).
// Per 2 activations: 2x v_cos + 3 packed-f32 ops.
__device__ __forceinline__ half8 act8(floatx4 a, floatx4 b) {
    float2v c0 = { __builtin_amdgcn_cosf(a[0]), __builtin_amdgcn_cosf(a[1]) };
    float2v c1 = { __builtin_amdgcn_cosf(a[2]), __builtin_amdgcn_cosf(a[3]) };
    float2v c2 = { __builtin_amdgcn_cosf(b[0]), __builtin_amdgcn_cosf(b[1]) };
    float2v c3 = { __builtin_amdgcn_cosf(b[2]), __builtin_amdgcn_cosf(b[3]) };
    float2v u0 = c0*c0, u1 = c1*c1, u2 = c2*c2, u3 = c3*c3;
    float2v t0 = __builtin_elementwise_fma(u0, (float2v)(ACT_D), (float2v)(ACT_B));
    float2v t1 = __builtin_elementwise_fma(u1, (float2v)(ACT_D), (float2v)(ACT_B));
    float2v t2 = __builtin_elementwise_fma(u2, (float2v)(ACT_D), (float2v)(ACT_B));
    float2v t3 = __builtin_elementwise_fma(u3, (float2v)(ACT_D), (float2v)(ACT_B));
    float2v h0 = __builtin_elementwise_fma(u0, t0, (float2v)(ACT_A));
    float2v h1 = __builtin_elementwise_fma(u1, t1, (float2v)(ACT_A));
    float2v h2 = __builtin_elementwise_fma(u2, t2, (float2v)(ACT_A));
    float2v h3 = __builtin_elementwise_fma(u3, t3, (float2v)(ACT_A));
    half2v e0 = __builtin_bit_cast(half2v, __builtin_amdgcn_cvt_pkrtz(h0.x, h0.y));
    half2v e1 = __builtin_bit_cast(half2v, __builtin_amdgcn_cvt_pkrtz(h1.x, h1.y));
    half2v e2 = __builtin_bit_cast(half2v, __builtin_amdgcn_cvt_pkrtz(h2.x, h2.y));
    half2v e3 = __builtin_bit_cast(half2v, __builtin_amdgcn_cvt_pkrtz(h3.x, h3.y));
    half4v lo = __builtin_shufflevector(e0, e1, 0, 1, 2, 3);
    half4v hi = __builtin_shufflevector(e2, e3, 0, 1, 2, 3);
    return __builtin_shufflevector(lo, hi, 0, 1, 2, 3, 4, 5, 6, 7);
}

// Per-block LDS weight cache: w2/w3 A-frags + f32 bias C-frags (R11-proven:
// biases MUST stay in LDS -- R12 put them in registers at the (512,8) 64-reg
// cap and got ~26 regs of scratch spill, FETCH 12.5->454 MB, dur 98->178 us).
// 512-thread block, 4 resident blocks/CU = 32 waves/CU ceiling at 98KB LDS.
struct SMem {
    half8   w2[8][64];   // [(t*2+c)][lane]
    half8   w3[8][64];
    floatx4 b2[4][64];   // [t][lane]
    floatx4 b3[4][64];
};

__global__ __launch_bounds__(512, 8) void mlp_fused(
    const float* __restrict__ x,
    const float* __restrict__ W1, const float* __restrict__ b1,
    const float* __restrict__ W2, const float* __restrict__ b2,
    const float* __restrict__ W3, const float* __restrict__ b3,
    const float* __restrict__ W4, const float* __restrict__ b4,
    float* __restrict__ out, int N)
{
    __shared__ SMem sm;
    const int lane = threadIdx.x & 63;
    const int wib  = threadIdx.x >> 6;   // 0..7
    const int m    = lane & 15;   // sample / C col / A row
    const int q    = lane >> 4;   // quad
    const float s  = INV2PI;
    const floatx4 zero4 = {0.0f, 0.0f, 0.0f, 0.0f};

    // ---- in-register persistent frags (small): L1 and L4 ----
    // L1 A-frag (tile t), lanes q==0: [w0h, w0h, w0l, w1h, w1h, w1l, b1h, b1l]
    half8 w1f[4];
    #pragma unroll
    for (int t = 0; t < 4; ++t) {
        half8 v = {};
        if (q == 0) {
            const int n = 16 * t + m;
            float w0 = W1[2*n] * s, w1 = W1[2*n+1] * s, bb = b1[n] * s;
            _Float16 w0h = (_Float16)w0; float w0l = w0 - (float)w0h;
            _Float16 w1h = (_Float16)w1; float w1l = w1 - (float)w1h;
            _Float16 bh  = (_Float16)bb; float bl  = bb - (float)bh;
            v[0] = w0h; v[1] = w0h; v[2] = (_Float16)w0l;
            v[3] = w1h; v[4] = w1h; v[5] = (_Float16)w1l;
            v[6] = bh;  v[7] = (_Float16)bl;
        }
        w1f[t] = v;
    }
    // L4 A-frag: only out-row m==0 real; sigma column permutation
    //   sigma: k-slot (c,q,j) -> neuron (j<4 ? 16c+4q+j : 16(c+2)+4q+j-4)
    half8 w4f[2] = {half8{}, half8{}};
    if (m == 0) {
        #pragma unroll
        for (int c = 0; c < 2; ++c)
            #pragma unroll
            for (int j = 0; j < 8; ++j) {
                int nu = (j < 4) ? (16 * c + 4 * q + j) : (16 * (c + 2) + 4 * q + j - 4);
                w4f[c][j] = (_Float16)(W4[nu] * s);
            }
    }
    floatx4 a4init = zero4;
    if (q == 0) a4init[0] = b4[0] * s;       // C row 0 = (q=0, r=0)

    // ---- wave-split LDS prep (sigma-permuted columns), one barrier ----
    if (wib == 0) {
        #pragma unroll
        for (int t = 0; t < 4; ++t) {
            const float* r2 = W2 + (16 * t + m) * 64;
            #pragma unroll
            for (int c = 0; c < 2; ++c) {
                floatx4 lo2 = *(const floatx4*)(r2 + 16 * c + 4 * q);
                floatx4 hi2 = *(const floatx4*)(r2 + 16 * (c + 2) + 4 * q);
                half8 v2;
                #pragma unroll
                for (int j = 0; j < 4; ++j) {
                    v2[j]     = (_Float16)(lo2[j] * s);
                    v2[4 + j] = (_Float16)(hi2[j] * s);
                }
                sm.w2[t * 2 + c][lane] = v2;
            }
        }
    } else if (wib == 1) {
        #pragma unroll
        for (int t = 0; t < 4; ++t) {
            const float* r3 = W3 + (16 * t + m) * 64;
            #pragma unroll
            for (int c = 0; c < 2; ++c) {
                floatx4 lo3 = *(const floatx4*)(r3 + 16 * c + 4 * q);
                floatx4 hi3 = *(const floatx4*)(r3 + 16 * (c + 2) + 4 * q);
                half8 v3;
                #pragma unroll
                for (int j = 0; j < 4; ++j) {
                    v3[j]     = (_Float16)(lo3[j] * s);
                    v3[4 + j] = (_Float16)(hi3[j] * s);
                }
                sm.w3[t * 2 + c][lane] = v3;
            }
        }
    } else if (wib == 2) {
        #pragma unroll
        for (int t = 0; t < 4; ++t) {
            sm.b2[t][lane] = *(const floatx4*)(b2 + 16 * t + 4 * q) * s;
            sm.b3[t][lane] = *(const floatx4*)(b3 + 16 * t + 4 * q) * s;
        }
    }
    __syncthreads();

    const int ntiles = N >> 4;
    const int nwaves = (gridDim.x * blockDim.x) >> 6;
    const int gwave  = (int)(blockIdx.x * blockDim.x + threadIdx.x) >> 6;
    const float2* __restrict__ x2 = (const float2*)x;

    int tile = gwave;
    float2 xv = x2[(tile << 4) + m];          // 1-ahead x prefetch
    while (tile < ntiles) {
        const int nt = tile + nwaves;
        float2 xnext;
        if (nt < ntiles) xnext = x2[(nt << 4) + m];

        // L1 B-frag (lanes q==0): [xh, xl, xh, yh, yl, yh, 1, 1]
        half8 xa = {};
        if (q == 0) {
            _Float16 xh = (_Float16)xv.x; float xl = xv.x - (float)xh;
            _Float16 yh = (_Float16)xv.y; float yl = xv.y - (float)yh;
            xa[0] = xh; xa[1] = (_Float16)xl; xa[2] = xh;
            xa[3] = yh; xa[4] = (_Float16)yl; xa[5] = yh;
            xa[6] = (_Float16)1.0f; xa[7] = (_Float16)1.0f;
        }

        // ---- layer 1 (in-register frags) ----
        floatx4 a0 = __builtin_amdgcn_mfma_f32_16x16x32_f16(w1f[0], xa, zero4, 0, 0, 0);
        floatx4 a1 = __builtin_amdgcn_mfma_f32_16x16x32_f16(w1f[1], xa, zero4, 0, 0, 0);
        floatx4 a2 = __builtin_amdgcn_mfma_f32_16x16x32_f16(w1f[2], xa, zero4, 0, 0, 0);
        floatx4 a3 = __builtin_amdgcn_mfma_f32_16x16x32_f16(w1f[3], xa, zero4, 0, 0, 0);
        half8 B0 = act8(a0, a2);
        half8 B1 = act8(a1, a3);

        // Opaque zero per layer: defeats LICM (else the LDS reads hoist back
        // into ~128 live regs and spill) AND staggers reads so peak staging
        // is one layer's worth.
        int z2 = 0; asm volatile("" : "+v"(z2));
        const int l2i = lane + z2;
        a0 = __builtin_amdgcn_mfma_f32_16x16x32_f16(sm.w2[0][l2i], B0, sm.b2[0][l2i], 0, 0, 0);
        a1 = __builtin_amdgcn_mfma_f32_16x16x32_f16(sm.w2[2][l2i], B0, sm.b2[1][l2i], 0, 0, 0);
        a2 = __builtin_amdgcn_mfma_f32_16x16x32_f16(sm.w2[4][l2i], B0, sm.b2[2][l2i], 0, 0, 0);
        a3 = __builtin_amdgcn_mfma_f32_16x16x32_f16(sm.w2[6][l2i], B0, sm.b2[3][l2i], 0, 0, 0);
        a0 = __builtin_amdgcn_mfma_f32_16x16x32_f16(sm.w2[1][l2i], B1, a0, 0, 0, 0);
        a1 = __builtin_amdgcn_mfma_f32_16x16x32_f16(sm.w2[3][l2i], B1, a1, 0, 0, 0);
        a2 = __builtin_amdgcn_mfma_f32_16x16x32_f16(sm.w2[5][l2i], B1, a2, 0, 0, 0);
        a3 = __builtin_amdgcn_mfma_f32_16x16x32_f16(sm.w2[7][l2i], B1, a3, 0, 0, 0);
        half8 C0 = act8(a0, a2);
        half8 C1 = act8(a1, a3);

        int z3 = 0; asm volatile("" : "+v"(z3));
        const int l3i = lane + z3;
        a0 = __builtin_amdgcn_mfma_f32_16x16x32_f16(sm.w3[0][l3i], C0, sm.b3[0][l3i], 0, 0, 0);
        a1 = __builtin_amdgcn_mfma_f32_16x16x32_f16(sm.w3[2][l3i], C0, sm.b3[1][l3i], 0, 0, 0);
        a2 = __builtin_amdgcn_mfma_f32_16x16x32_f16(sm.w3[4][l3i], C0, sm.b3[2][l3i], 0, 0, 0);
        a3 = __builtin_amdgcn_mfma_f32_16x16x32_f16(sm.w3[6][l3i], C0, sm.b3[3][l3i], 0, 0, 0);
        a0 = __builtin_amdgcn_mfma_f32_16x16x32_f16(sm.w3[1][l3i], C1, a0, 0, 0, 0);
        a1 = __builtin_amdgcn_mfma_f32_16x16x32_f16(sm.w3[3][l3i], C1, a1, 0, 0, 0);
        a2 = __builtin_amdgcn_mfma_f32_16x16x32_f16(sm.w3[5][l3i], C1, a2, 0, 0, 0);
        a3 = __builtin_amdgcn_mfma_f32_16x16x32_f16(sm.w3[7][l3i], C1, a3, 0, 0, 0);
        half8 D0 = act8(a0, a2);
        half8 D1 = act8(a1, a3);

        // ---- layer 4 + store ----
        floatx4 a4 = __builtin_amdgcn_mfma_f32_16x16x32_f16(w4f[0], D0, a4init, 0, 0, 0);
        a4 = __builtin_amdgcn_mfma_f32_16x16x32_f16(w4f[1], D1, a4, 0, 0, 0);
        if (q == 0)
            out[(tile << 4) + m] = act_rev(a4[0]);

        xv = xnext;
        tile = nt;
    }
}

extern "C" void kernel_launch(void* const* d_in, const int* in_sizes, int n_in,
                              void* d_out, int out_size, void* d_ws, size_t ws_size,
                              hipStream_t stream) {
    const float* x  = (const float*)d_in[0];
    const float* W1 = (const float*)d_in[1];
    const float* b1 = (const float*)d_in[2];
    const float* W2 = (const float*)d_in[3];
    const float* b2 = (const float*)d_in[4];
    const float* W3 = (const float*)d_in[5];
    const float* b3 = (const float*)d_in[6];
    const float* W4 = (const float*)d_in[7];
    const float* b4 = (const float*)d_in[8];
    float* out = (float*)d_out;
    const int N = out_size;          // 2097152, divisible by 16

    // 1024 blocks x 8 waves = 8192 waves, ALL co-resident (4 blocks/CU);
    // 131072 tiles -> exactly 16 tiles/wave. Single dispatch round.
    mlp_fused<<<dim3(1024), dim3(512), 0, stream>>>(x, W1, b1, W2, b2, W3, b3, W4, b4, out, N);
}